// Round 10
// baseline (86.756 us; speedup 1.0000x reference)
//
#include <hip/hip_runtime.h>
#include <math.h>

#define EPSF    1e-8f
#define W_MINF  0.005f
#define BETAF   0.02f
#define LOG2E   1.4426950408889634f

constexpr double KD    = 1.4426950408889634 / 0.02;   // log2(e)/beta
constexpr float  K2F   = (float)(KD * KD);            // folded into A,B,C
constexpr float  K2EPS = (float)(KD * KD * 1e-8);     // scaled eps
constexpr float  INVK  = (float)(1.0 / KD);

typedef float v2f __attribute__((ext_vector_type(2)));
typedef float v4f __attribute__((ext_vector_type(4)));

__device__ __forceinline__ float fast_exp(float x) {   // e^x
    return __builtin_amdgcn_exp2f(x * LOG2E);
}
__device__ __forceinline__ float sigm(float x) {       // 1/(1+e^-x)
    return 1.0f / (1.0f + fast_exp(-x));
}
__device__ __forceinline__ float ex2(float x) { return __builtin_amdgcn_exp2f(x); }

__device__ __forceinline__ unsigned min3u(unsigned a, unsigned b, unsigned c) {
    unsigned d;
    asm("v_min3_u32 %0, %1, %2, %3" : "=v"(d) : "v"(a), "v"(b), "v"(c));
    return d;
}
__device__ __forceinline__ unsigned med3u(unsigned a, unsigned b, unsigned c) {
    unsigned d;
    asm("v_med3_u32 %0, %1, %2, %3" : "=v"(d) : "v"(a), "v"(b), "v"(c));
    return d;
}

// M=2 register blocking: each lane owns queries q and q+64, so every
// wave-uniform seed broadcast (the scarce LDS-pipe resource) serves 2x the
// distance evals. 512 thr/block = 8 waves = 8 seed partitions of 64;
// block covers 128 queries; grid 512 -> 2 blocks/CU.
extern "C" __global__ __launch_bounds__(512, 8)
void voronoi_kernel(const float* __restrict__ uv,
                    const float* __restrict__ seeds,
                    const float* __restrict__ theta,
                    const float* __restrict__ a_raw,
                    const float* __restrict__ w_raw,
                    const float* __restrict__ h_raw,
                    const float* __restrict__ gap_thr_raw,
                    const float* __restrict__ big_thr_raw,
                    const float* __restrict__ alpha_raw,
                    const float* __restrict__ eta_raw,
                    float* __restrict__ out,
                    int Q, int S)
{
    __shared__ float sg[128 * 20];                    // 10 KB seed table
    __shared__ unsigned mv1[8][128], mv2[8][128];     //  8 KB
    __shared__ float    ms1[8][128], ms2[8][128];     //  8 KB

    const int tid = threadIdx.x;
    {   // in-block seed prep: thread tid preps seed tid (blockDim == S == 512)
        const int j = tid;
        float sx = seeds[2 * j + 0];
        float sy = seeds[2 * j + 1];
        float sn, cs;
        __sincosf(theta[j], &sn, &cs);
        float a   = 0.5f + 1.5f * sigm(a_raw[j]);
        float a2  = a * a;
        float ia2 = 1.0f / a2;
        float c2 = cs * cs, s2 = sn * sn;
        float* p = &sg[(j >> 2) * 20 + (j & 3)];
        p[0]  = K2F * (c2 * a2 + s2 * ia2);           // A
        p[4]  = K2F * (s2 * a2 + c2 * ia2);           // B
        p[8]  = K2F * (cs * sn * (a2 - ia2));         // C
        p[12] = sx;                                   // X
        p[16] = sy;                                   // Y
    }
    __syncthreads();

    const int part = __builtin_amdgcn_readfirstlane((int)(tid >> 6));
    const int lane = tid & 63;
    const int q0   = blockIdx.x * 128 + lane;         // query A
    const int q1   = q0 + 64;                         // query B
    const int qa   = q0 < Q ? q0 : (Q - 1);
    const int qb   = q1 < Q ? q1 : (Q - 1);

    const float2 uA = *reinterpret_cast<const float2*>(&uv[2 * qa]);
    const float2 uB = *reinterpret_cast<const float2*>(&uv[2 * qb]);
    const v2f uxA = { uA.x, uA.x }, uyA = { uA.y, uA.y };
    const v2f uxB = { uB.x, uB.x }, uyB = { uB.y, uB.y };
    const v2f epsv = { K2EPS, K2EPS };

    unsigned v1A = 0x7F7FFFFFu, v2A = 0x7F7FFFFFu;    // packed (r|idx), query A
    unsigned v1B = 0x7F7FFFFFu, v2B = 0x7F7FFFFFu;    // query B
    v2f s1Av = { 0.0f, 0.0f }, s2Av = { 0.0f, 0.0f };
    v2f s1Bv = { 0.0f, 0.0f }, s2Bv = { 0.0f, 0.0f };

    const int gbase = part * 16;                      // 16 groups = 64 seeds
    #pragma unroll 4
    for (int g = 0; g < 16; ++g) {
        const float* pp = &sg[(gbase + g) * 20];      // wave-uniform broadcast
        const v4f Av = *reinterpret_cast<const v4f*>(pp + 0);
        const v4f Bv = *reinterpret_cast<const v4f*>(pp + 4);
        const v4f Cv = *reinterpret_cast<const v4f*>(pp + 8);
        const v4f Xv = *reinterpret_cast<const v4f*>(pp + 12);
        const v4f Yv = *reinterpret_cast<const v4f*>(pp + 16);

        #pragma unroll
        for (int h = 0; h < 2; ++h) {                 // 2 seed-pairs per group
            const v2f A = h ? (v2f){Av.z, Av.w} : (v2f){Av.x, Av.y};
            const v2f B = h ? (v2f){Bv.z, Bv.w} : (v2f){Bv.x, Bv.y};
            const v2f C = h ? (v2f){Cv.z, Cv.w} : (v2f){Cv.x, Cv.y};
            const v2f X = h ? (v2f){Xv.z, Xv.w} : (v2f){Xv.x, Xv.y};
            const v2f Y = h ? (v2f){Yv.z, Yv.w} : (v2f){Yv.x, Yv.y};
            const int j0 = (gbase + g) * 4 + 2 * h;

            // ---- query A ----
            {
                v2f dx = uxA - X;
                v2f dy = uyA - Y;
                v2f p  = __builtin_elementwise_fma(A, dx, C * dy);
                v2f qv = __builtin_elementwise_fma(C, dx, B * dy);
                v2f r  = __builtin_elementwise_fma(
                             dx, p, __builtin_elementwise_fma(dy, qv, epsv));
                float e0 = ex2(-__builtin_amdgcn_sqrtf(r.x));
                float e1 = ex2(-__builtin_amdgcn_sqrtf(r.y));
                v2f e = { e0, e1 };
                s1Av = s1Av + e;
                s2Av = __builtin_elementwise_fma(e, e, s2Av);
                unsigned pv0 = (__float_as_uint(r.x) & 0xFFFFFE00u) | (unsigned)j0;
                unsigned pv1 = (__float_as_uint(r.y) & 0xFFFFFE00u) | (unsigned)(j0 + 1);
                unsigned m2  = med3u(v1A, pv0, pv1);
                v1A = min3u(v1A, pv0, pv1);
                v2A = v2A < m2 ? v2A : m2;
            }
            // ---- query B ----
            {
                v2f dx = uxB - X;
                v2f dy = uyB - Y;
                v2f p  = __builtin_elementwise_fma(A, dx, C * dy);
                v2f qv = __builtin_elementwise_fma(C, dx, B * dy);
                v2f r  = __builtin_elementwise_fma(
                             dx, p, __builtin_elementwise_fma(dy, qv, epsv));
                float e0 = ex2(-__builtin_amdgcn_sqrtf(r.x));
                float e1 = ex2(-__builtin_amdgcn_sqrtf(r.y));
                v2f e = { e0, e1 };
                s1Bv = s1Bv + e;
                s2Bv = __builtin_elementwise_fma(e, e, s2Bv);
                unsigned pv0 = (__float_as_uint(r.x) & 0xFFFFFE00u) | (unsigned)j0;
                unsigned pv1 = (__float_as_uint(r.y) & 0xFFFFFE00u) | (unsigned)(j0 + 1);
                unsigned m2  = med3u(v1B, pv0, pv1);
                v1B = min3u(v1B, pv0, pv1);
                v2B = v2B < m2 ? v2B : m2;
            }
        }
    }

    // ---- stash per-wave partials (2 queries per lane) --------------------
    mv1[part][lane]      = v1A;  mv2[part][lane]      = v2A;
    ms1[part][lane]      = s1Av.x + s1Av.y;
    ms2[part][lane]      = s2Av.x + s2Av.y;
    mv1[part][lane + 64] = v1B;  mv2[part][lane + 64] = v2B;
    ms1[part][lane + 64] = s1Bv.x + s1Bv.y;
    ms2[part][lane + 64] = s2Bv.x + s2Bv.y;
    __syncthreads();
    if (part != 0) return;

    // wave 0's 64 lanes merge + finish both of their queries
    #pragma unroll
    for (int m = 0; m < 2; ++m) {
        const int qi = lane + 64 * m;
        const int qq = blockIdx.x * 128 + qi;

        unsigned V1 = mv1[0][qi], V2 = mv2[0][qi];
        float    S1 = ms1[0][qi], S2 = ms2[0][qi];
        #pragma unroll
        for (int p2 = 1; p2 < 8; ++p2) {
            unsigned w1 = mv1[p2][qi], w2 = mv2[p2][qi];
            S1 += ms1[p2][qi];
            S2 += ms2[p2][qi];
            unsigned n1 = V1 < w1 ? V1 : w1;
            unsigned hi = V1 > w1 ? V1 : w1;
            unsigned l2 = V2 < w2 ? V2 : w2;
            V2 = hi < l2 ? hi : l2;
            V1 = n1;
        }

        const int i1 = (int)(V1 & 511u);
        const int i2 = (int)(V2 & 511u);
        float d1K = __builtin_amdgcn_sqrtf(__uint_as_float(V1));   // K*d1
        float d2K = __builtin_amdgcn_sqrtf(__uint_as_float(V2));
        float d1  = d1K * INVK;
        float gap = (d2K - d1K) * INVK;

        float sp2  = (S2 / S1) / S1;                 // sum p^2 (underflow-safe)
        float keff = 1.0f / (sp2 + EPSF);
        float jfac = sigm((keff - 3.0f) * (1.0f / 0.35f));

        float x1 = sg[(i1 >> 2) * 20 + 12 + (i1 & 3)];
        float y1 = sg[(i1 >> 2) * 20 + 16 + (i1 & 3)];
        float x2 = sg[(i2 >> 2) * 20 + 12 + (i2 & 3)];
        float y2 = sg[(i2 >> 2) * 20 + 16 + (i2 & 3)];
        float ddx   = x1 - x2;
        float ddy   = y1 - y2;
        float pdist = __builtin_amdgcn_sqrtf(fmaf(ddx, ddx, fmaf(ddy, ddy, EPSF)));
        float wmax  = fmaxf(0.8f * pdist, W_MINF + EPSF);
        float sij   = sigm(w_raw[i1 * S + i2] * 0.2f);   // /RAW_TEMP(5)
        float sji   = sigm(w_raw[i2 * S + i1] * 0.2f);
        float wpair = W_MINF + (wmax - W_MINF) * 0.5f * (sij + sji);

        float weff     = wpair * fmaf(0.15f, jfac, 1.0f);
        float beta_eff = BETAF * fmaf(0.05f, jfac, 1.0f);
        float wall     = sigm((weff - gap) / beta_eff);

        float gap_thr = 0.5f  * sigm(gap_thr_raw[0]);
        float big_thr = 0.6f  * sigm(big_thr_raw[0]);
        float alpha_g = 0.01f + 0.19f * sigm(alpha_raw[0]);
        float eta_g   = 0.01f + 0.19f * sigm(eta_raw[0]);

        float gate = sigm((gap_thr - gap) / alpha_g) * sigm((big_thr - d1) / eta_g);

        float t      = fmaxf(keff - 3.0f, 0.0f);
        float triple = 0.15f * t * __builtin_amdgcn_sqrtf(t);

        float hh  = 0.5f + 1.5f * sigm(h_raw[0]);
        float occ = fminf(fmaxf(fmaf(wall, gate, triple), 0.0f), 1.0f);
        if (qq < Q) out[qq] = occ * hh;
    }
}

extern "C" void kernel_launch(void* const* d_in, const int* in_sizes, int n_in,
                              void* d_out, int out_size, void* d_ws, size_t ws_size,
                              hipStream_t stream)
{
    const float* uv          = (const float*)d_in[0];
    const float* seeds_raw   = (const float*)d_in[1];
    const float* w_raw       = (const float*)d_in[2];
    const float* h_raw       = (const float*)d_in[3];
    const float* theta       = (const float*)d_in[4];
    const float* a_raw       = (const float*)d_in[5];
    const float* gap_thr_raw = (const float*)d_in[6];
    const float* big_thr_raw = (const float*)d_in[7];
    const float* alpha_raw   = (const float*)d_in[8];
    const float* eta_raw     = (const float*)d_in[9];
    float* out = (float*)d_out;

    const int Q = in_sizes[0] / 2;
    const int S = in_sizes[4];

    dim3 block(512);                      // 8 waves: 8 seed-partitions
    dim3 grid((Q + 127) / 128);           // 128 queries per block (M=2/lane)
    voronoi_kernel<<<grid, block, 0, stream>>>(uv, seeds_raw, theta, a_raw,
                                               w_raw, h_raw,
                                               gap_thr_raw, big_thr_raw,
                                               alpha_raw, eta_raw,
                                               out, Q, S);
}